// Round 1
// baseline (18746.483 us; speedup 1.0000x reference)
//
#include <hip/hip_runtime.h>

#define NB 4096   // batch
#define NH 1024   // hidden
#define NE 512    // embedding dim
#define NV 23     // vocab
#define NT 64     // seq len
#define NL 144    // latent+cond
#define PADV 21
#define SOSV 22

typedef unsigned short u16;
typedef __attribute__((ext_vector_type(4))) float f32x4;
typedef __attribute__((ext_vector_type(8))) __bf16 bf16x8;

__device__ __forceinline__ u16 f2bf(float x) {
  unsigned u = __float_as_uint(x);
  u += 0x7FFFu + ((u >> 16) & 1u);   // RNE to bf16
  return (u16)(u >> 16);
}
__device__ __forceinline__ float bf2f(u16 h) {
  return __uint_as_float(((unsigned)h) << 16);
}

// ---------------------------------------------------------------------------
// prep: split W_hh into bf16 hi/lo, zero c, init tokens to SOS
__global__ void prep_kernel(const float* __restrict__ Whh, u16* __restrict__ Whi,
                            u16* __restrict__ Wlo, float* __restrict__ c,
                            int* __restrict__ tok) {
  int i = blockIdx.x * 256 + threadIdx.x;   // exactly 4*NH*NH = NB*NH threads
  float wv = Whh[i];
  u16 hi = f2bf(wv);
  Whi[i] = hi;
  Wlo[i] = f2bf(wv - bf2f(hi));
  c[i] = 0.0f;
  if (i < NB) tok[i] = SOSV;
}

// ---------------------------------------------------------------------------
// ExW[v][n] = b_ih[n] + b_hh[n] + sum_k E'[v][k] * W_ih[n][k]   (E' pad row = 0)
__global__ void exw_kernel(const float* __restrict__ emb, const float* __restrict__ Wih,
                           const float* __restrict__ bih, const float* __restrict__ bhh,
                           float* __restrict__ ExW) {
  __shared__ float Es[NE];
  const int v = blockIdx.y;
  const int n = blockIdx.x * 256 + threadIdx.x;
  for (int k = threadIdx.x; k < NE; k += 256)
    Es[k] = (v == PADV) ? 0.0f : emb[v * NE + k];
  __syncthreads();
  float s = bih[n] + bhh[n];
  const float* wr = Wih + (long)n * NE;
  for (int k = 0; k < NE; ++k) s = fmaf(Es[k], wr[k], s);
  ExW[v * (4 * NH) + n] = s;
}

// ---------------------------------------------------------------------------
// h0 = [z, cond] @ W_lh^T + b_lh  -> split into bf16 hi/lo
__global__ void h0_kernel(const float* __restrict__ z, const float* __restrict__ cnd,
                          const float* __restrict__ Wlh, const float* __restrict__ blh,
                          u16* __restrict__ hhi, u16* __restrict__ hlo) {
  __shared__ float zc[8][NL];
  const int b0 = blockIdx.y * 8;
  const int j = blockIdx.x * 256 + threadIdx.x;
  for (int idx = threadIdx.x; idx < 8 * NL; idx += 256) {
    int bi = idx / NL, k = idx % NL;
    zc[bi][k] = (k < 128) ? z[(long)(b0 + bi) * 128 + k]
                          : cnd[(long)(b0 + bi) * 16 + (k - 128)];
  }
  __syncthreads();
  float acc[8];
  const float bj = blh[j];
#pragma unroll
  for (int bi = 0; bi < 8; ++bi) acc[bi] = bj;
  const float* wr = Wlh + (long)j * NL;
  for (int k = 0; k < NL; ++k) {
    float wv = wr[k];
#pragma unroll
    for (int bi = 0; bi < 8; ++bi) acc[bi] = fmaf(wv, zc[bi][k], acc[bi]);
  }
#pragma unroll
  for (int bi = 0; bi < 8; ++bi) {
    long idx = (long)(b0 + bi) * NH + j;
    u16 hi = f2bf(acc[bi]);
    hhi[idx] = hi;
    hlo[idx] = f2bf(acc[bi] - bf2f(hi));
  }
}

// ---------------------------------------------------------------------------
// Fused gates GEMM (split-bf16, 3 MFMA products) + LSTM cell epilogue.
// Block: 256 thr (4 waves). Tile: 128 (m) x 32 (j) x 4 gates. BK=32.
// LDS layout [kc][row][8 bf16] is both global_load_lds-linear (dest = base+lane*16)
// and conflict-free for ds_read_b128 fragment reads.
__global__ __launch_bounds__(256, 2)
void gates_cell_kernel(const u16* __restrict__ Whi, const u16* __restrict__ Wlo,
                       const u16* __restrict__ hhi_in, const u16* __restrict__ hlo_in,
                       const float* __restrict__ ExW, const int* __restrict__ tok,
                       float* __restrict__ c, u16* __restrict__ hhi_out,
                       u16* __restrict__ hlo_out) {
  __shared__ u16 Ahi[4 * 128 * 8];
  __shared__ u16 Alo[4 * 128 * 8];
  __shared__ u16 Bhi[4 * 128 * 8];
  __shared__ u16 Blo[4 * 128 * 8];

  const int bid = blockIdx.x;
  const int swz = (bid & 7) * 128 + (bid >> 3);   // XCD-contiguous chunks (1024 = 8*128)
  const int m0 = (swz >> 5) * 128;
  const int j0 = (swz & 31) * 32;
  const int tid = threadIdx.x;
  const int w = tid >> 6;
  const int l = tid & 63;

  // staging role per wave: 0->A_hi 1->A_lo 2->B_hi 3->B_lo
  const u16* src;
  u16* ldsw;
  if (w == 0)      { src = hhi_in; ldsw = Ahi; }
  else if (w == 1) { src = hlo_in; ldsw = Alo; }
  else if (w == 2) { src = Whi;    ldsw = Bhi; }
  else             { src = Wlo;    ldsw = Blo; }

  long row0, row1;  // per-lane element offsets of this lane's source rows (rb=0/1)
  if (w < 2) {
    row0 = (long)(m0 + l) * NH;
    row1 = (long)(m0 + 64 + l) * NH;
  } else {
    const int r0 = l, r1 = l + 64;  // LDS B row = g*32 + jl ; W row = g*NH + j0 + jl
    row0 = (long)((r0 >> 5) * NH + j0 + (r0 & 31)) * NH;
    row1 = (long)((r1 >> 5) * NH + j0 + (r1 & 31)) * NH;
  }

  f32x4 acc[4][2][2];
#pragma unroll
  for (int g = 0; g < 4; ++g)
#pragma unroll
    for (int mi = 0; mi < 2; ++mi)
#pragma unroll
      for (int ji = 0; ji < 2; ++ji)
        acc[g][mi][ji] = (f32x4){0.f, 0.f, 0.f, 0.f};

  const int kcL = l >> 4;   // lane's k-chunk for fragment reads
  const int rL = l & 15;    // lane's row-in-tile / output column

  for (int k0 = 0; k0 < NH; k0 += 32) {
#pragma unroll
    for (int kc = 0; kc < 4; ++kc) {
      __builtin_amdgcn_global_load_lds(
          (const __attribute__((address_space(1))) void*)(src + row0 + k0 + kc * 8),
          (__attribute__((address_space(3))) void*)(ldsw + kc * 1024), 16, 0, 0);
      __builtin_amdgcn_global_load_lds(
          (const __attribute__((address_space(1))) void*)(src + row1 + k0 + kc * 8),
          (__attribute__((address_space(3))) void*)(ldsw + kc * 1024 + 512), 16, 0, 0);
    }
    __syncthreads();

    bf16x8 a_hi[2], a_lo[2];
#pragma unroll
    for (int mi = 0; mi < 2; ++mi) {
      const int ro = kcL * 1024 + (w * 32 + mi * 16 + rL) * 8;
      a_hi[mi] = *reinterpret_cast<const bf16x8*>(&Ahi[ro]);
      a_lo[mi] = *reinterpret_cast<const bf16x8*>(&Alo[ro]);
    }
#pragma unroll
    for (int g = 0; g < 4; ++g) {
#pragma unroll
      for (int ji = 0; ji < 2; ++ji) {
        const int ro = kcL * 1024 + (g * 32 + ji * 16 + rL) * 8;
        const bf16x8 b_hi = *reinterpret_cast<const bf16x8*>(&Bhi[ro]);
        const bf16x8 b_lo = *reinterpret_cast<const bf16x8*>(&Blo[ro]);
#pragma unroll
        for (int mi = 0; mi < 2; ++mi) {
          acc[g][mi][ji] = __builtin_amdgcn_mfma_f32_16x16x32_bf16(a_hi[mi], b_hi, acc[g][mi][ji], 0, 0, 0);
          acc[g][mi][ji] = __builtin_amdgcn_mfma_f32_16x16x32_bf16(a_hi[mi], b_lo, acc[g][mi][ji], 0, 0, 0);
          acc[g][mi][ji] = __builtin_amdgcn_mfma_f32_16x16x32_bf16(a_lo[mi], b_hi, acc[g][mi][ji], 0, 0, 0);
        }
      }
    }
    __syncthreads();
  }

  // epilogue: add ExW[token] (x-part + bias), LSTM cell, split new h to bf16 hi/lo
#pragma unroll
  for (int mi = 0; mi < 2; ++mi) {
#pragma unroll
    for (int r = 0; r < 4; ++r) {
      const int m = m0 + w * 32 + mi * 16 + kcL * 4 + r;  // C/D row = (l>>4)*4 + reg
      const int tk = tok[m];
      const float* exr = ExW + (long)tk * (4 * NH);
#pragma unroll
      for (int ji = 0; ji < 2; ++ji) {
        const int j = j0 + ji * 16 + rL;                  // C/D col = lane&15
        const float gi = acc[0][mi][ji][r] + exr[j];
        const float gf = acc[1][mi][ji][r] + exr[NH + j];
        const float gg = acc[2][mi][ji][r] + exr[2 * NH + j];
        const float go = acc[3][mi][ji][r] + exr[3 * NH + j];
        const float i_ = 1.0f / (1.0f + expf(-gi));
        const float f_ = 1.0f / (1.0f + expf(-gf));
        const float g_ = tanhf(gg);
        const float o_ = 1.0f / (1.0f + expf(-go));
        const long idx = (long)m * NH + j;
        const float cn = f_ * c[idx] + i_ * g_;
        c[idx] = cn;
        const float hn = o_ * tanhf(cn);
        const u16 hi = f2bf(hn);
        hhi_out[idx] = hi;
        hlo_out[idx] = f2bf(hn - bf2f(hi));
      }
    }
  }
}

// ---------------------------------------------------------------------------
// logits = h @ W_out^T + b_out ; write out[:, t, :]; tok = argmax (first max).
// One block handles 4 batch rows to reuse W_out loads.
__global__ __launch_bounds__(256)
void logits_kernel(const u16* __restrict__ hhi, const u16* __restrict__ hlo,
                   const float* __restrict__ Wout, const float* __restrict__ bout,
                   float* __restrict__ out, int* __restrict__ tok, int t) {
  __shared__ float hs[4][NH];
  __shared__ float part[8][24][4];
  __shared__ float lg[4][24];
  const int b0 = blockIdx.x * 4;
  const int tid = threadIdx.x;
  for (int idx = tid; idx < 4 * NH; idx += 256) {
    int bi = idx >> 10, k = idx & (NH - 1);
    long gidx = (long)(b0 + bi) * NH + k;
    hs[bi][k] = bf2f(hhi[gidx]) + bf2f(hlo[gidx]);
  }
  __syncthreads();
  const int v = tid & 31, kc = tid >> 5;
  if (v < NV) {
    float s0 = 0.f, s1 = 0.f, s2 = 0.f, s3 = 0.f;
    const float* wr = Wout + (long)v * NH + kc * 128;
    const int kb = kc * 128;
    for (int k = 0; k < 128; ++k) {
      float wv = wr[k];
      s0 = fmaf(wv, hs[0][kb + k], s0);
      s1 = fmaf(wv, hs[1][kb + k], s1);
      s2 = fmaf(wv, hs[2][kb + k], s2);
      s3 = fmaf(wv, hs[3][kb + k], s3);
    }
    part[kc][v][0] = s0; part[kc][v][1] = s1;
    part[kc][v][2] = s2; part[kc][v][3] = s3;
  }
  __syncthreads();
  if (tid < NV * 4) {
    const int vv = tid >> 2, bi = tid & 3;
    float s = bout[vv];
#pragma unroll
    for (int k = 0; k < 8; ++k) s += part[k][vv][bi];
    lg[bi][vv] = s;
    out[((long)(b0 + bi) * NT + t) * NV + vv] = s;
  }
  __syncthreads();
  if (tid < 4) {
    float best = lg[tid][0];
    int bv = 0;
    for (int vv = 1; vv < NV; ++vv) {
      float x = lg[tid][vv];
      if (x > best) { best = x; bv = vv; }   // strict > : first-max like np.argmax
    }
    tok[b0 + tid] = bv;
  }
}

// ---------------------------------------------------------------------------
extern "C" void kernel_launch(void* const* d_in, const int* in_sizes, int n_in,
                              void* d_out, int out_size, void* d_ws, size_t ws_size,
                              hipStream_t stream) {
  const float* z    = (const float*)d_in[0];
  const float* cnd  = (const float*)d_in[1];
  const float* emb  = (const float*)d_in[2];
  const float* Wlh  = (const float*)d_in[3];
  const float* blh  = (const float*)d_in[4];
  const float* Wih  = (const float*)d_in[5];
  const float* Whh  = (const float*)d_in[6];
  const float* bih  = (const float*)d_in[7];
  const float* bhh  = (const float*)d_in[8];
  const float* Wout = (const float*)d_in[9];
  const float* bout = (const float*)d_in[10];
  float* out = (float*)d_out;

  char* ws = (char*)d_ws;
  size_t off = 0;
  auto alloc = [&](size_t bytes) -> void* {
    off = (off + 255) & ~(size_t)255;
    void* p = ws + off;
    off += bytes;
    return p;
  };
  u16* Whi = (u16*)alloc((size_t)4 * NH * NH * 2);
  u16* Wlo = (u16*)alloc((size_t)4 * NH * NH * 2);
  float* ExW = (float*)alloc((size_t)NV * 4 * NH * 4);
  u16* hhi0 = (u16*)alloc((size_t)NB * NH * 2);
  u16* hhi1 = (u16*)alloc((size_t)NB * NH * 2);
  u16* hlo0 = (u16*)alloc((size_t)NB * NH * 2);
  u16* hlo1 = (u16*)alloc((size_t)NB * NH * 2);
  float* cbuf = (float*)alloc((size_t)NB * NH * 4);
  int* tokb = (int*)alloc((size_t)NB * 4);
  u16* hhi[2] = {hhi0, hhi1};
  u16* hlo[2] = {hlo0, hlo1};

  prep_kernel<<<dim3((4 * NH * NH) / 256), dim3(256), 0, stream>>>(Whh, Whi, Wlo, cbuf, tokb);
  exw_kernel<<<dim3((4 * NH) / 256, NV), dim3(256), 0, stream>>>(emb, Wih, bih, bhh, ExW);
  h0_kernel<<<dim3(NH / 256, NB / 8), dim3(256), 0, stream>>>(z, cnd, Wlh, blh, hhi[0], hlo[0]);

  int p = 0;
  for (int t = 0; t < NT; ++t) {
    gates_cell_kernel<<<dim3(1024), dim3(256), 0, stream>>>(
        Whi, Wlo, hhi[p], hlo[p], ExW, tokb, cbuf, hhi[p ^ 1], hlo[p ^ 1]);
    logits_kernel<<<dim3(NB / 4), dim3(256), 0, stream>>>(
        hhi[p ^ 1], hlo[p ^ 1], Wout, bout, out, tokb, t);
    p ^= 1;
  }
}

// Round 2
// 6582.926 us; speedup vs baseline: 2.8477x; 2.8477x over previous
//
#include <hip/hip_runtime.h>

#define NB 4096   // batch
#define NH 1024   // hidden
#define NE 512    // embedding dim
#define NV 23     // vocab
#define NT 64     // seq len
#define NL 144    // latent+cond
#define PADV 21
#define SOSV 22

typedef unsigned short u16;
typedef __attribute__((ext_vector_type(4))) float f32x4;
typedef __attribute__((ext_vector_type(8))) __bf16 bf16x8;
typedef __attribute__((ext_vector_type(8))) unsigned short u16x8;

__device__ __forceinline__ u16 f2bf(float x) {
  unsigned u = __float_as_uint(x);
  u += 0x7FFFu + ((u >> 16) & 1u);   // RNE to bf16
  return (u16)(u >> 16);
}
__device__ __forceinline__ float bf2f(u16 h) {
  return __uint_as_float(((unsigned)h) << 16);
}

// h image layout: [mt=m>>8][ks=j>>5][q=(j>>3)&3][row=m&255][e=j&7]
// (j is the HIDDEN index = k of the next step's GEMM; image == LDS A-tile image)
__device__ __forceinline__ size_t hidx(int m, int j) {
  return ((size_t)(((m >> 8) * 32 + (j >> 5)) * 4 + ((j >> 3) & 3)) * 2048)
         + (size_t)((m & 255) * 8) + (j & 7);
}

// ---------------------------------------------------------------------------
// prep: split W_hh into bf16 hi/lo *images* (blocked LDS layout), zero c, SOS tok.
// W image: [jt=jcol>>6][ks=k>>5][q=(k>>3)&3][row][e=k&7], row = (jl>>4)*64 + g*16 + (jl&15)
__global__ void prep_kernel(const float* __restrict__ Whh, u16* __restrict__ Whi,
                            u16* __restrict__ Wlo, float* __restrict__ c,
                            int* __restrict__ tok) {
  int i = blockIdx.x * 256 + threadIdx.x;   // 4M threads = 4*NH*NH = NB*NH
  float wv = Whh[i];
  u16 hi = f2bf(wv);
  u16 lo = f2bf(wv - bf2f(hi));
  const int nw = i >> 10, k = i & 1023;
  const int g = nw >> 10, jcol = nw & 1023;
  const int jt = jcol >> 6, jl = jcol & 63;
  const int row = ((jl >> 4) << 6) + (g << 4) + (jl & 15);
  const size_t oi = ((size_t)((jt * 32 + (k >> 5)) * 4 + ((k >> 3) & 3)) * 2048)
                    + (size_t)(row * 8) + (k & 7);
  Whi[oi] = hi;
  Wlo[oi] = lo;
  c[i] = 0.0f;
  if (i < NB) tok[i] = SOSV;
}

// ---------------------------------------------------------------------------
// ExW[v][n] = b_ih[n] + b_hh[n] + sum_k E'[v][k] * W_ih[n][k]   (E' pad row = 0)
__global__ void exw_kernel(const float* __restrict__ emb, const float* __restrict__ Wih,
                           const float* __restrict__ bih, const float* __restrict__ bhh,
                           float* __restrict__ ExW) {
  __shared__ float Es[NE];
  const int v = blockIdx.y;
  const int n = blockIdx.x * 256 + threadIdx.x;
  for (int k = threadIdx.x; k < NE; k += 256)
    Es[k] = (v == PADV) ? 0.0f : emb[v * NE + k];
  __syncthreads();
  float s = bih[n] + bhh[n];
  const float* wr = Wih + (long)n * NE;
  for (int k = 0; k < NE; ++k) s = fmaf(Es[k], wr[k], s);
  ExW[v * (4 * NH) + n] = s;
}

// ---------------------------------------------------------------------------
// h0 = [z, cond] @ W_lh^T + b_lh  -> split into bf16 hi/lo, written in h-image layout
__global__ void h0_kernel(const float* __restrict__ z, const float* __restrict__ cnd,
                          const float* __restrict__ Wlh, const float* __restrict__ blh,
                          u16* __restrict__ hhi, u16* __restrict__ hlo) {
  __shared__ float zc[8][NL];
  const int b0 = blockIdx.y * 8;
  const int j = blockIdx.x * 256 + threadIdx.x;
  for (int idx = threadIdx.x; idx < 8 * NL; idx += 256) {
    int bi = idx / NL, k = idx % NL;
    zc[bi][k] = (k < 128) ? z[(long)(b0 + bi) * 128 + k]
                          : cnd[(long)(b0 + bi) * 16 + (k - 128)];
  }
  __syncthreads();
  float acc[8];
  const float bj = blh[j];
#pragma unroll
  for (int bi = 0; bi < 8; ++bi) acc[bi] = bj;
  const float* wr = Wlh + (long)j * NL;
  for (int k = 0; k < NL; ++k) {
    float wv = wr[k];
#pragma unroll
    for (int bi = 0; bi < 8; ++bi) acc[bi] = fmaf(wv, zc[bi][k], acc[bi]);
  }
#pragma unroll
  for (int bi = 0; bi < 8; ++bi) {
    size_t idx = hidx(b0 + bi, j);
    u16 hi = f2bf(acc[bi]);
    hhi[idx] = hi;
    hlo[idx] = f2bf(acc[bi] - bf2f(hi));
  }
}

// ---------------------------------------------------------------------------
__device__ __forceinline__ void stage8(const u16* __restrict__ src, u16* dst) {
#pragma unroll
  for (int i = 0; i < 8; ++i)
    __builtin_amdgcn_global_load_lds(
        (const __attribute__((address_space(1))) void*)(src + i * 512),
        (__attribute__((address_space(3))) void*)(dst + i * 512), 16, 0, 0);
}

// Fused gates GEMM (split-bf16, 3 MFMA products) + LSTM cell epilogue.
// 512 thr (8 waves: 4 m-waves x 2 n-waves). Block tile: 256 m x (64 j x 4 g). BK=32.
// Double-buffered 128 KiB LDS; all staging loads contiguous 1KB (prepacked images).
__global__ __launch_bounds__(512, 2)
void gates_cell_kernel(const u16* __restrict__ Whi, const u16* __restrict__ Wlo,
                       const u16* __restrict__ hhi_in, const u16* __restrict__ hlo_in,
                       const float* __restrict__ ExW, const int* __restrict__ tok,
                       float* __restrict__ c, u16* __restrict__ hhi_out,
                       u16* __restrict__ hlo_out) {
  __shared__ u16 lds[65536];   // [4 mats][2 dbuf][8192] : Ahi Alo Bhi Blo

  const int bid = blockIdx.x;                 // 256 blocks = 16 mt x 16 jt
  const int swz = (bid & 7) * 32 + (bid >> 3);  // XCD x owns jt {2x,2x+1} (W slice L2-fits)
  const int jt = swz >> 4;
  const int mt = swz & 15;
  const int m0 = mt << 8;
  const int j0 = jt << 6;

  const int tid = threadIdx.x;
  const int w = tid >> 6, l = tid & 63;
  const int wm = w >> 1, wn = w & 1;
  const int q = l >> 4, rL = l & 15;

  // staging role: mat = w>>1 (0 Ahi,1 Alo,2 Bhi,3 Blo), hf = w&1 picks 8KB half
  const int mat = w >> 1, hf = w & 1;
  const u16* simg = (mat == 0) ? hhi_in : (mat == 1) ? hlo_in : (mat == 2) ? Whi : Wlo;
  const size_t sbase = ((mat < 2) ? ((size_t)mt * 262144) : ((size_t)jt * 262144))
                       + (size_t)hf * 4096 + (size_t)l * 8;
  const u16* sit = simg + sbase;                    // + ks*8192 per K-step
  u16* dwave = (u16*)lds + mat * 16384 + hf * 4096; // + buf*8192

  f32x4 acc[4][8];
#pragma unroll
  for (int mi = 0; mi < 4; ++mi)
#pragma unroll
    for (int ni = 0; ni < 8; ++ni) acc[mi][ni] = (f32x4){0.f, 0.f, 0.f, 0.f};

  const int qoff = q * 2048 + rL * 8;

  stage8(sit, dwave);           // prologue: stage ks=0 into buf 0
  __syncthreads();

  int buf = 0;
  for (int ks = 0; ks < 32; ++ks) {
    if (ks < 31) stage8(sit + (size_t)(ks + 1) * 8192, dwave + (buf ^ 1) * 8192);

    bf16x8 ah[4], al[4];
    const u16* ab = lds + buf * 8192 + qoff + wm * 512;
#pragma unroll
    for (int mi = 0; mi < 4; ++mi) {
      ah[mi] = *reinterpret_cast<const bf16x8*>(ab + mi * 128);
      al[mi] = *reinterpret_cast<const bf16x8*>(ab + 16384 + mi * 128);
    }
    const u16* bb = lds + 32768 + buf * 8192 + qoff + wn * 1024;
#pragma unroll
    for (int ni = 0; ni < 8; ++ni) {
      const bf16x8 bh = *reinterpret_cast<const bf16x8*>(bb + ni * 128);
      const bf16x8 bl = *reinterpret_cast<const bf16x8*>(bb + 16384 + ni * 128);
#pragma unroll
      for (int mi = 0; mi < 4; ++mi)
        acc[mi][ni] = __builtin_amdgcn_mfma_f32_16x16x32_bf16(ah[mi], bh, acc[mi][ni], 0, 0, 0);
#pragma unroll
      for (int mi = 0; mi < 4; ++mi)
        acc[mi][ni] = __builtin_amdgcn_mfma_f32_16x16x32_bf16(ah[mi], bl, acc[mi][ni], 0, 0, 0);
#pragma unroll
      for (int mi = 0; mi < 4; ++mi)
        acc[mi][ni] = __builtin_amdgcn_mfma_f32_16x16x32_bf16(al[mi], bh, acc[mi][ni], 0, 0, 0);
    }
    __syncthreads();   // drains stage (vmcnt0) + guards dbuf reuse
    buf ^= 1;
  }

  // epilogue: + ExW[token], LSTM cell (fp32), write h hi/lo in image layout
#pragma unroll
  for (int mi = 0; mi < 4; ++mi) {
#pragma unroll
    for (int r = 0; r < 4; ++r) {
      const int m = m0 + wm * 64 + mi * 16 + q * 4 + r;   // C row = (lane>>4)*4 + reg
      const int tk = tok[m];
      const float* exr = ExW + (size_t)tk * 4096;
#pragma unroll
      for (int jh = 0; jh < 2; ++jh) {
        const int j = j0 + (wn * 2 + jh) * 16 + rL;        // C col = lane&15
        const float gi = acc[mi][jh * 4 + 0][r] + exr[j];
        const float gf = acc[mi][jh * 4 + 1][r] + exr[NH + j];
        const float gg = acc[mi][jh * 4 + 2][r] + exr[2 * NH + j];
        const float go = acc[mi][jh * 4 + 3][r] + exr[3 * NH + j];
        const float i_ = 1.0f / (1.0f + expf(-gi));
        const float f_ = 1.0f / (1.0f + expf(-gf));
        const float g_ = tanhf(gg);
        const float o_ = 1.0f / (1.0f + expf(-go));
        const size_t cidx = (size_t)m * NH + j;
        const float cn = f_ * c[cidx] + i_ * g_;
        c[cidx] = cn;
        const float hn = o_ * tanhf(cn);
        const u16 hi = f2bf(hn);
        const size_t oidx = hidx(m, j);
        hhi_out[oidx] = hi;
        hlo_out[oidx] = f2bf(hn - bf2f(hi));
      }
    }
  }
}

// ---------------------------------------------------------------------------
// logits = h @ W_out^T + b_out ; write out[:, t, :]; tok = argmax (first max).
__global__ __launch_bounds__(256)
void logits_kernel(const u16* __restrict__ hhi, const u16* __restrict__ hlo,
                   const float* __restrict__ Wout, const float* __restrict__ bout,
                   float* __restrict__ out, int* __restrict__ tok, int t) {
  __shared__ float hs[4][NH];
  __shared__ float part[8][24][4];
  __shared__ float lg[4][24];
  const int b0 = blockIdx.x * 4;
  const int tid = threadIdx.x;
  // gather h from image layout: 512 jobs = 4 batches x 128 16B-chunks (hi+lo summed)
  for (int ci = tid; ci < 512; ci += 256) {
    const int bi = ci >> 7, cj = ci & 127;
    const int m = b0 + bi;
    const int ks = cj >> 2, qq = cj & 3;
    const size_t base = ((size_t)(((m >> 8) * 32 + ks) * 4 + qq) * 2048)
                        + (size_t)((m & 255) * 8);
    const u16x8 vh = *reinterpret_cast<const u16x8*>(hhi + base);
    const u16x8 vl = *reinterpret_cast<const u16x8*>(hlo + base);
    const int kb = ks * 32 + qq * 8;
#pragma unroll
    for (int e = 0; e < 8; ++e) hs[bi][kb + e] = bf2f(vh[e]) + bf2f(vl[e]);
  }
  __syncthreads();
  const int v = tid & 31, kc = tid >> 5;
  if (v < NV) {
    float s0 = 0.f, s1 = 0.f, s2 = 0.f, s3 = 0.f;
    const float* wr = Wout + (long)v * NH + kc * 128;
    const int kb = kc * 128;
    for (int k = 0; k < 128; ++k) {
      float wv = wr[k];
      s0 = fmaf(wv, hs[0][kb + k], s0);
      s1 = fmaf(wv, hs[1][kb + k], s1);
      s2 = fmaf(wv, hs[2][kb + k], s2);
      s3 = fmaf(wv, hs[3][kb + k], s3);
    }
    part[kc][v][0] = s0; part[kc][v][1] = s1;
    part[kc][v][2] = s2; part[kc][v][3] = s3;
  }
  __syncthreads();
  if (tid < NV * 4) {
    const int vv = tid >> 2, bi = tid & 3;
    float s = bout[vv];
#pragma unroll
    for (int k = 0; k < 8; ++k) s += part[k][vv][bi];
    lg[bi][vv] = s;
    out[((long)(b0 + bi) * NT + t) * NV + vv] = s;
  }
  __syncthreads();
  if (tid < 4) {
    float best = lg[tid][0];
    int bv = 0;
    for (int vv = 1; vv < NV; ++vv) {
      float x = lg[tid][vv];
      if (x > best) { best = x; bv = vv; }   // strict > : first-max like np.argmax
    }
    tok[b0 + tid] = bv;
  }
}

// ---------------------------------------------------------------------------
extern "C" void kernel_launch(void* const* d_in, const int* in_sizes, int n_in,
                              void* d_out, int out_size, void* d_ws, size_t ws_size,
                              hipStream_t stream) {
  const float* z    = (const float*)d_in[0];
  const float* cnd  = (const float*)d_in[1];
  const float* emb  = (const float*)d_in[2];
  const float* Wlh  = (const float*)d_in[3];
  const float* blh  = (const float*)d_in[4];
  const float* Wih  = (const float*)d_in[5];
  const float* Whh  = (const float*)d_in[6];
  const float* bih  = (const float*)d_in[7];
  const float* bhh  = (const float*)d_in[8];
  const float* Wout = (const float*)d_in[9];
  const float* bout = (const float*)d_in[10];
  float* out = (float*)d_out;

  char* ws = (char*)d_ws;
  size_t off = 0;
  auto alloc = [&](size_t bytes) -> void* {
    off = (off + 255) & ~(size_t)255;
    void* p = ws + off;
    off += bytes;
    return p;
  };
  u16* Whi = (u16*)alloc((size_t)4 * NH * NH * 2);
  u16* Wlo = (u16*)alloc((size_t)4 * NH * NH * 2);
  float* ExW = (float*)alloc((size_t)NV * 4 * NH * 4);
  u16* hhi0 = (u16*)alloc((size_t)NB * NH * 2);
  u16* hhi1 = (u16*)alloc((size_t)NB * NH * 2);
  u16* hlo0 = (u16*)alloc((size_t)NB * NH * 2);
  u16* hlo1 = (u16*)alloc((size_t)NB * NH * 2);
  float* cbuf = (float*)alloc((size_t)NB * NH * 4);
  int* tokb = (int*)alloc((size_t)NB * 4);
  u16* hhi[2] = {hhi0, hhi1};
  u16* hlo[2] = {hlo0, hlo1};

  prep_kernel<<<dim3((4 * NH * NH) / 256), dim3(256), 0, stream>>>(Whh, Whi, Wlo, cbuf, tokb);
  exw_kernel<<<dim3((4 * NH) / 256, NV), dim3(256), 0, stream>>>(emb, Wih, bih, bhh, ExW);
  h0_kernel<<<dim3(NH / 256, NB / 8), dim3(256), 0, stream>>>(z, cnd, Wlh, blh, hhi[0], hlo[0]);

  int p = 0;
  for (int t = 0; t < NT; ++t) {
    gates_cell_kernel<<<dim3(256), dim3(512), 0, stream>>>(
        Whi, Wlo, hhi[p], hlo[p], ExW, tokb, cbuf, hhi[p ^ 1], hlo[p ^ 1]);
    logits_kernel<<<dim3(NB / 4), dim3(256), 0, stream>>>(
        hhi[p ^ 1], hlo[p ^ 1], Wout, bout, out, tokb, t);
    p ^= 1;
  }
}

// Round 3
// 6329.632 us; speedup vs baseline: 2.9617x; 1.0400x over previous
//
#include <hip/hip_runtime.h>

#define NB 4096   // batch
#define NH 1024   // hidden
#define NE 512    // embedding dim
#define NV 23     // vocab
#define NT 64     // seq len
#define NL 144    // latent+cond
#define PADV 21
#define SOSV 22

typedef unsigned short u16;
typedef __attribute__((ext_vector_type(4))) float f32x4;
typedef __attribute__((ext_vector_type(8))) __bf16 bf16x8;
typedef __attribute__((ext_vector_type(8))) unsigned short u16x8;

__device__ __forceinline__ u16 f2bf(float x) {
  unsigned u = __float_as_uint(x);
  u += 0x7FFFu + ((u >> 16) & 1u);   // RNE to bf16
  return (u16)(u >> 16);
}
__device__ __forceinline__ float bf2f(u16 h) {
  return __uint_as_float(((unsigned)h) << 16);
}

// h image layout: [mt=m>>8][ks=j>>5][q=(j>>3)&3][row=m&255][e=j&7]
__device__ __forceinline__ size_t hidx(int m, int j) {
  return ((size_t)(((m >> 8) * 32 + (j >> 5)) * 4 + ((j >> 3) & 3)) * 2048)
         + (size_t)((m & 255) * 8) + (j & 7);
}

// ---------------------------------------------------------------------------
// prep: split W_hh into bf16 hi/lo *images* (blocked LDS layout), zero c, SOS tok.
__global__ void prep_kernel(const float* __restrict__ Whh, u16* __restrict__ Whi,
                            u16* __restrict__ Wlo, float* __restrict__ c,
                            int* __restrict__ tok) {
  int i = blockIdx.x * 256 + threadIdx.x;   // 4M threads = 4*NH*NH = NB*NH
  float wv = Whh[i];
  u16 hi = f2bf(wv);
  u16 lo = f2bf(wv - bf2f(hi));
  const int nw = i >> 10, k = i & 1023;
  const int g = nw >> 10, jcol = nw & 1023;
  const int jt = jcol >> 6, jl = jcol & 63;
  const int row = ((jl >> 4) << 6) + (g << 4) + (jl & 15);
  const size_t oi = ((size_t)((jt * 32 + (k >> 5)) * 4 + ((k >> 3) & 3)) * 2048)
                    + (size_t)(row * 8) + (k & 7);
  Whi[oi] = hi;
  Wlo[oi] = lo;
  c[i] = 0.0f;
  if (i < NB) tok[i] = SOSV;
}

// ---------------------------------------------------------------------------
__global__ void exw_kernel(const float* __restrict__ emb, const float* __restrict__ Wih,
                           const float* __restrict__ bih, const float* __restrict__ bhh,
                           float* __restrict__ ExW) {
  __shared__ float Es[NE];
  const int v = blockIdx.y;
  const int n = blockIdx.x * 256 + threadIdx.x;
  for (int k = threadIdx.x; k < NE; k += 256)
    Es[k] = (v == PADV) ? 0.0f : emb[v * NE + k];
  __syncthreads();
  float s = bih[n] + bhh[n];
  const float* wr = Wih + (long)n * NE;
  for (int k = 0; k < NE; ++k) s = fmaf(Es[k], wr[k], s);
  ExW[v * (4 * NH) + n] = s;
}

// ---------------------------------------------------------------------------
__global__ void h0_kernel(const float* __restrict__ z, const float* __restrict__ cnd,
                          const float* __restrict__ Wlh, const float* __restrict__ blh,
                          u16* __restrict__ hhi, u16* __restrict__ hlo) {
  __shared__ float zc[8][NL];
  const int b0 = blockIdx.y * 8;
  const int j = blockIdx.x * 256 + threadIdx.x;
  for (int idx = threadIdx.x; idx < 8 * NL; idx += 256) {
    int bi = idx / NL, k = idx % NL;
    zc[bi][k] = (k < 128) ? z[(long)(b0 + bi) * 128 + k]
                          : cnd[(long)(b0 + bi) * 16 + (k - 128)];
  }
  __syncthreads();
  float acc[8];
  const float bj = blh[j];
#pragma unroll
  for (int bi = 0; bi < 8; ++bi) acc[bi] = bj;
  const float* wr = Wlh + (long)j * NL;
  for (int k = 0; k < NL; ++k) {
    float wv = wr[k];
#pragma unroll
    for (int bi = 0; bi < 8; ++bi) acc[bi] = fmaf(wv, zc[bi][k], acc[bi]);
  }
#pragma unroll
  for (int bi = 0; bi < 8; ++bi) {
    size_t idx = hidx(b0 + bi, j);
    u16 hi = f2bf(acc[bi]);
    hhi[idx] = hi;
    hlo[idx] = f2bf(acc[bi] - bf2f(hi));
  }
}

// ---------------------------------------------------------------------------
__device__ __forceinline__ void stage1(const u16* __restrict__ src, u16* dst, int i) {
  __builtin_amdgcn_global_load_lds(
      (const __attribute__((address_space(1))) void*)(src + i * 512),
      (__attribute__((address_space(3))) void*)(dst + i * 512), 16, 0, 0);
}

// Fused gates GEMM (split-bf16, 3 MFMA products) + LSTM cell epilogue.
// 512 thr (8 waves). Tile: 256 m x (64 j x 4 g). BK=32. Double-buffered 128 KiB LDS.
// 4-phase schedule per K-iter: {reads + stage | raw barrier | setprio-MFMA cluster}.
__global__ __launch_bounds__(512, 2)
void gates_cell_kernel(const u16* __restrict__ Whi, const u16* __restrict__ Wlo,
                       const u16* __restrict__ hhi_in, const u16* __restrict__ hlo_in,
                       const float* __restrict__ ExW, const int* __restrict__ tok,
                       float* __restrict__ c, u16* __restrict__ hhi_out,
                       u16* __restrict__ hlo_out) {
  __shared__ u16 lds[65536];   // [4 mats][2 dbuf][8192] : Ahi Alo Bhi Blo

  const int bid = blockIdx.x;                   // 256 blocks = 16 mt x 16 jt
  const int swz = (bid & 7) * 32 + (bid >> 3);  // XCD x owns jt {2x,2x+1}
  const int jt = swz >> 4;
  const int mt = swz & 15;
  const int m0 = mt << 8;
  const int j0 = jt << 6;

  const int tid = threadIdx.x;
  const int w = tid >> 6, l = tid & 63;
  const int wm = w >> 1, wn = w & 1;
  const int q = l >> 4, rL = l & 15;

  const int mat = w >> 1, hf = w & 1;
  const u16* simg = (mat == 0) ? hhi_in : (mat == 1) ? hlo_in : (mat == 2) ? Whi : Wlo;
  const size_t sbase = ((mat < 2) ? ((size_t)mt * 262144) : ((size_t)jt * 262144))
                       + (size_t)hf * 4096 + (size_t)l * 8;
  const u16* sit = simg + sbase;
  u16* dwave = (u16*)lds + mat * 16384 + hf * 4096;

  // prefetch greedy tokens for this thread's 16 output rows (oldest vmem; retire first)
  int tkv[16];
#pragma unroll
  for (int mi = 0; mi < 4; ++mi)
#pragma unroll
    for (int r = 0; r < 4; ++r)
      tkv[mi * 4 + r] = tok[m0 + wm * 64 + mi * 16 + q * 4 + r];

  f32x4 acc[4][8];
#pragma unroll
  for (int mi = 0; mi < 4; ++mi)
#pragma unroll
    for (int ni = 0; ni < 8; ++ni) acc[mi][ni] = (f32x4){0.f, 0.f, 0.f, 0.f};

  const int qoff = q * 2048 + rL * 8;

#pragma unroll
  for (int i = 0; i < 8; ++i) stage1(sit, dwave, i);   // prologue: ks=0 -> buf0
  asm volatile("s_waitcnt vmcnt(0)" ::: "memory");
  __builtin_amdgcn_s_barrier();
  __builtin_amdgcn_sched_barrier(0);

  int buf = 0;
  for (int ks = 0; ks < 32; ++ks) {
    const u16* ab = lds + buf * 8192 + qoff + wm * 512;
    const u16* bb = lds + 32768 + buf * 8192 + qoff + wn * 1024;
    const u16* snext = sit + (size_t)(ks + 1) * 8192;
    u16* dnext = dwave + (buf ^ 1) * 8192;
    bf16x8 ah[4], al[4];

#pragma unroll
    for (int ph = 0; ph < 4; ++ph) {
      // ---- phase reads (this phase's fragments) ----
      if (ph == 0) {
#pragma unroll
        for (int mi = 0; mi < 4; ++mi) {
          ah[mi] = *reinterpret_cast<const bf16x8*>(ab + mi * 128);
          al[mi] = *reinterpret_cast<const bf16x8*>(ab + 16384 + mi * 128);
        }
      }
      bf16x8 bh0 = *reinterpret_cast<const bf16x8*>(bb + (2 * ph + 0) * 128);
      bf16x8 bl0 = *reinterpret_cast<const bf16x8*>(bb + 16384 + (2 * ph + 0) * 128);
      bf16x8 bh1 = *reinterpret_cast<const bf16x8*>(bb + (2 * ph + 1) * 128);
      bf16x8 bl1 = *reinterpret_cast<const bf16x8*>(bb + 16384 + (2 * ph + 1) * 128);
      // ---- stage next K-tile, spread over phases 0..2 ----
      if (ks < 31) {
        if (ph == 0) { stage1(snext, dnext, 0); stage1(snext, dnext, 1); stage1(snext, dnext, 2); }
        if (ph == 1) { stage1(snext, dnext, 3); stage1(snext, dnext, 4); stage1(snext, dnext, 5); }
        if (ph == 2) { stage1(snext, dnext, 6); stage1(snext, dnext, 7); }
      }
      // ---- phase barrier (scheduling shaper; intra-iter order is correctness-free) ----
      __builtin_amdgcn_sched_barrier(0);
      __builtin_amdgcn_s_barrier();
      __builtin_amdgcn_sched_barrier(0);
      // ---- MFMA cluster ----
      __builtin_amdgcn_s_setprio(1);
#pragma unroll
      for (int mi = 0; mi < 4; ++mi)
        acc[mi][2 * ph + 0] = __builtin_amdgcn_mfma_f32_16x16x32_bf16(ah[mi], bh0, acc[mi][2 * ph + 0], 0, 0, 0);
#pragma unroll
      for (int mi = 0; mi < 4; ++mi)
        acc[mi][2 * ph + 0] = __builtin_amdgcn_mfma_f32_16x16x32_bf16(ah[mi], bl0, acc[mi][2 * ph + 0], 0, 0, 0);
#pragma unroll
      for (int mi = 0; mi < 4; ++mi)
        acc[mi][2 * ph + 0] = __builtin_amdgcn_mfma_f32_16x16x32_bf16(al[mi], bh0, acc[mi][2 * ph + 0], 0, 0, 0);
#pragma unroll
      for (int mi = 0; mi < 4; ++mi)
        acc[mi][2 * ph + 1] = __builtin_amdgcn_mfma_f32_16x16x32_bf16(ah[mi], bh1, acc[mi][2 * ph + 1], 0, 0, 0);
#pragma unroll
      for (int mi = 0; mi < 4; ++mi)
        acc[mi][2 * ph + 1] = __builtin_amdgcn_mfma_f32_16x16x32_bf16(ah[mi], bl1, acc[mi][2 * ph + 1], 0, 0, 0);
#pragma unroll
      for (int mi = 0; mi < 4; ++mi)
        acc[mi][2 * ph + 1] = __builtin_amdgcn_mfma_f32_16x16x32_bf16(al[mi], bh1, acc[mi][2 * ph + 1], 0, 0, 0);
      __builtin_amdgcn_s_setprio(0);
      __builtin_amdgcn_sched_barrier(0);
    }

    // ---- iter boundary: all stages landed, then buffer swap ----
    if (ks < 31) {
      asm volatile("s_waitcnt vmcnt(0)" ::: "memory");
      __builtin_amdgcn_s_barrier();
      __builtin_amdgcn_sched_barrier(0);
    }
    buf ^= 1;
  }

  // epilogue: + ExW[token], LSTM cell (fp32), write h hi/lo in image layout
#pragma unroll
  for (int mi = 0; mi < 4; ++mi) {
#pragma unroll
    for (int r = 0; r < 4; ++r) {
      const int m = m0 + wm * 64 + mi * 16 + q * 4 + r;   // C row = (lane>>4)*4 + reg
      const float* exr = ExW + (size_t)tkv[mi * 4 + r] * 4096;
#pragma unroll
      for (int jh = 0; jh < 2; ++jh) {
        const int j = j0 + (wn * 2 + jh) * 16 + rL;        // C col = lane&15
        const float gi = acc[mi][jh * 4 + 0][r] + exr[j];
        const float gf = acc[mi][jh * 4 + 1][r] + exr[NH + j];
        const float gg = acc[mi][jh * 4 + 2][r] + exr[2 * NH + j];
        const float go = acc[mi][jh * 4 + 3][r] + exr[3 * NH + j];
        const float i_ = 1.0f / (1.0f + expf(-gi));
        const float f_ = 1.0f / (1.0f + expf(-gf));
        const float g_ = tanhf(gg);
        const float o_ = 1.0f / (1.0f + expf(-go));
        const size_t cidx = (size_t)m * NH + j;
        const float cn = f_ * c[cidx] + i_ * g_;
        c[cidx] = cn;
        const float hn = o_ * tanhf(cn);
        const u16 hi = f2bf(hn);
        const size_t oidx = hidx(m, j);
        hhi_out[oidx] = hi;
        hlo_out[oidx] = f2bf(hn - bf2f(hi));
      }
    }
  }
}

// ---------------------------------------------------------------------------
// logits = h @ W_out^T + b_out ; 8 batch rows per block (amortize W_out reads).
__global__ __launch_bounds__(256)
void logits_kernel(const u16* __restrict__ hhi, const u16* __restrict__ hlo,
                   const float* __restrict__ Wout, const float* __restrict__ bout,
                   float* __restrict__ out, int* __restrict__ tok, int t) {
  __shared__ float hs[8][NH];
  __shared__ float part[8][24][8];
  __shared__ float lg[8][24];
  const int b0 = blockIdx.x * 8;
  const int tid = threadIdx.x;
  for (int ci = tid; ci < 1024; ci += 256) {
    const int bi = ci >> 7, cj = ci & 127;
    const int m = b0 + bi;
    const int ks = cj >> 2, qq = cj & 3;
    const size_t base = ((size_t)(((m >> 8) * 32 + ks) * 4 + qq) * 2048)
                        + (size_t)((m & 255) * 8);
    const u16x8 vh = *reinterpret_cast<const u16x8*>(hhi + base);
    const u16x8 vl = *reinterpret_cast<const u16x8*>(hlo + base);
    const int kb = ks * 32 + qq * 8;
#pragma unroll
    for (int e = 0; e < 8; ++e) hs[bi][kb + e] = bf2f(vh[e]) + bf2f(vl[e]);
  }
  __syncthreads();
  const int v = tid & 31, kc = tid >> 5;
  if (v < NV) {
    float s[8];
#pragma unroll
    for (int bi = 0; bi < 8; ++bi) s[bi] = 0.f;
    const float* wr = Wout + (long)v * NH + kc * 128;
    const int kb = kc * 128;
    for (int k = 0; k < 128; ++k) {
      float wv = wr[k];
#pragma unroll
      for (int bi = 0; bi < 8; ++bi) s[bi] = fmaf(wv, hs[bi][kb + k], s[bi]);
    }
#pragma unroll
    for (int bi = 0; bi < 8; ++bi) part[kc][v][bi] = s[bi];
  }
  __syncthreads();
  if (tid < NV * 8) {
    const int vv = tid >> 3, bi = tid & 7;
    float s = bout[vv];
#pragma unroll
    for (int k = 0; k < 8; ++k) s += part[k][vv][bi];
    lg[bi][vv] = s;
    out[((long)(b0 + bi) * NT + t) * NV + vv] = s;
  }
  __syncthreads();
  if (tid < 8) {
    float best = lg[tid][0];
    int bv = 0;
    for (int vv = 1; vv < NV; ++vv) {
      float x = lg[tid][vv];
      if (x > best) { best = x; bv = vv; }   // strict > : first-max like np.argmax
    }
    tok[b0 + tid] = bv;
  }
}

// ---------------------------------------------------------------------------
extern "C" void kernel_launch(void* const* d_in, const int* in_sizes, int n_in,
                              void* d_out, int out_size, void* d_ws, size_t ws_size,
                              hipStream_t stream) {
  const float* z    = (const float*)d_in[0];
  const float* cnd  = (const float*)d_in[1];
  const float* emb  = (const float*)d_in[2];
  const float* Wlh  = (const float*)d_in[3];
  const float* blh  = (const float*)d_in[4];
  const float* Wih  = (const float*)d_in[5];
  const float* Whh  = (const float*)d_in[6];
  const float* bih  = (const float*)d_in[7];
  const float* bhh  = (const float*)d_in[8];
  const float* Wout = (const float*)d_in[9];
  const float* bout = (const float*)d_in[10];
  float* out = (float*)d_out;

  char* ws = (char*)d_ws;
  size_t off = 0;
  auto alloc = [&](size_t bytes) -> void* {
    off = (off + 255) & ~(size_t)255;
    void* p = ws + off;
    off += bytes;
    return p;
  };
  u16* Whi = (u16*)alloc((size_t)4 * NH * NH * 2);
  u16* Wlo = (u16*)alloc((size_t)4 * NH * NH * 2);
  float* ExW = (float*)alloc((size_t)NV * 4 * NH * 4);
  u16* hhi0 = (u16*)alloc((size_t)NB * NH * 2);
  u16* hhi1 = (u16*)alloc((size_t)NB * NH * 2);
  u16* hlo0 = (u16*)alloc((size_t)NB * NH * 2);
  u16* hlo1 = (u16*)alloc((size_t)NB * NH * 2);
  float* cbuf = (float*)alloc((size_t)NB * NH * 4);
  int* tokb = (int*)alloc((size_t)NB * 4);
  u16* hhi[2] = {hhi0, hhi1};
  u16* hlo[2] = {hlo0, hlo1};

  prep_kernel<<<dim3((4 * NH * NH) / 256), dim3(256), 0, stream>>>(Whh, Whi, Wlo, cbuf, tokb);
  exw_kernel<<<dim3((4 * NH) / 256, NV), dim3(256), 0, stream>>>(emb, Wih, bih, bhh, ExW);
  h0_kernel<<<dim3(NH / 256, NB / 8), dim3(256), 0, stream>>>(z, cnd, Wlh, blh, hhi[0], hlo[0]);

  int p = 0;
  for (int t = 0; t < NT; ++t) {
    gates_cell_kernel<<<dim3(256), dim3(512), 0, stream>>>(
        Whi, Wlo, hhi[p], hlo[p], ExW, tokb, cbuf, hhi[p ^ 1], hlo[p ^ 1]);
    logits_kernel<<<dim3(NB / 8), dim3(256), 0, stream>>>(
        hhi[p ^ 1], hlo[p ^ 1], Wout, bout, out, tokb, t);
    p ^= 1;
  }
}